// Round 1
// baseline (259.830 us; speedup 1.0000x reference)
//
#include <hip/hip_runtime.h>
#include <hip/hip_bf16.h>

// QuantizedLinear: out[64,11008] = x[64,4096] @ (Wq*scale)^T + bias
// Memory-bound: 180 MB int32 weight stream dominates. bf16 MFMA for compute.

#define M_DIM 64
#define N_DIM 11008
#define K_DIM 4096
#define KSPLIT 8
#define KC (K_DIM / KSPLIT)   // 512
#define BK 128
#define LDS_STRIDE 136        // 128 + 8 pad (bf16 units); keeps 16B alignment (272B rows)
#define BLOCK_N 64            // 4 waves x 16 N each

typedef __attribute__((ext_vector_type(8))) short bf16x8;
typedef __attribute__((ext_vector_type(4))) float f32x4;
typedef __attribute__((ext_vector_type(4))) int i32x4;
typedef __attribute__((ext_vector_type(4))) short s16x4;

// int in [-128,127] -> bf16 is EXACT: cvt to f32 then truncate mantissa (low 16 bits are zero)
__device__ __forceinline__ short i2bf(int q) {
    float f = (float)q;
    return (short)(__builtin_bit_cast(unsigned int, f) >> 16);
}

// RNE float -> bf16 (x inputs are normal floats; NaN not expected)
__device__ __forceinline__ short f2bf(float f) {
    unsigned int u = __builtin_bit_cast(unsigned int, f);
    u = u + 0x7FFFu + ((u >> 16) & 1u);
    return (short)(u >> 16);
}

__global__ __launch_bounds__(256) void init_bias_kernel(const float* __restrict__ bias,
                                                        float* __restrict__ out) {
    // 176128 float4 total = 64 * 2752
    int idx = blockIdx.x * 256 + threadIdx.x;
    int col4 = idx % 2752;               // N/4
    f32x4 b = *(const f32x4*)(bias + col4 * 4);
    *(f32x4*)(out + (size_t)idx * 4) = b;
}

__global__ __launch_bounds__(256) void qlinear_kernel(const float* __restrict__ x,
                                                      const int* __restrict__ wq,
                                                      const float* __restrict__ scale_p,
                                                      float* __restrict__ out) {
    __shared__ short lds[M_DIM * LDS_STRIDE];  // 17408 B

    const int tid  = threadIdx.x;
    const int wave = tid >> 6;
    const int lane = tid & 63;
    const int quad = lane >> 4;
    const int l16  = lane & 15;

    const int n0  = blockIdx.x * BLOCK_N;
    const int kc0 = blockIdx.y * KC;
    const float scale = *scale_p;

    // weight row this lane feeds into B fragments
    const int nw = n0 + wave * 16 + l16;
    const int* wptr = wq + (size_t)nw * K_DIM + kc0 + quad * 8;

    f32x4 acc[4] = {f32x4{0,0,0,0}, f32x4{0,0,0,0}, f32x4{0,0,0,0}, f32x4{0,0,0,0}};

    for (int kb = 0; kb < KC; kb += BK) {
        // ---- stage x[0:64][kc0+kb : +BK] into LDS as bf16 ----
        {
            const float* xbase = x + kc0 + kb;
            #pragma unroll
            for (int j = 0; j < 8; ++j) {
                int f  = tid + j * 256;      // 2048 float4 per tile
                int row = f >> 5;            // 32 float4 per row
                int c4  = f & 31;
                f32x4 v = *(const f32x4*)(xbase + (size_t)row * K_DIM + c4 * 4);
                s16x4 h;
                h.x = f2bf(v.x); h.y = f2bf(v.y); h.z = f2bf(v.z); h.w = f2bf(v.w);
                *(s16x4*)&lds[row * LDS_STRIDE + c4 * 4] = h;
            }
        }
        __syncthreads();

        #pragma unroll
        for (int kk = 0; kk < BK; kk += 32) {
            // B fragment: 8 consecutive int32 of weight row nw at k = kc0+kb+kk+quad*8
            i32x4 b0 = *(const i32x4*)(wptr + kb + kk);
            i32x4 b1 = *(const i32x4*)(wptr + kb + kk + 4);
            bf16x8 bfrag;
            bfrag[0] = i2bf(b0.x); bfrag[1] = i2bf(b0.y);
            bfrag[2] = i2bf(b0.z); bfrag[3] = i2bf(b0.w);
            bfrag[4] = i2bf(b1.x); bfrag[5] = i2bf(b1.y);
            bfrag[6] = i2bf(b1.z); bfrag[7] = i2bf(b1.w);

            #pragma unroll
            for (int mi = 0; mi < 4; ++mi) {
                bf16x8 afrag = *(const bf16x8*)&lds[(mi * 16 + l16) * LDS_STRIDE + kk + quad * 8];
                acc[mi] = __builtin_amdgcn_mfma_f32_16x16x32_bf16(afrag, bfrag, acc[mi], 0, 0, 0);
            }
        }
        __syncthreads();
    }

    // ---- epilogue: scale + atomic accumulate (K-split partials) ----
    const int nout = n0 + wave * 16 + l16;
    #pragma unroll
    for (int mi = 0; mi < 4; ++mi) {
        #pragma unroll
        for (int r = 0; r < 4; ++r) {
            int m = mi * 16 + quad * 4 + r;
            atomicAdd(&out[(size_t)m * N_DIM + nout], acc[mi][r] * scale);
        }
    }
}

extern "C" void kernel_launch(void* const* d_in, const int* in_sizes, int n_in,
                              void* d_out, int out_size, void* d_ws, size_t ws_size,
                              hipStream_t stream) {
    const float* x      = (const float*)d_in[0];
    const int*   wq     = (const int*)d_in[1];
    const float* scale  = (const float*)d_in[2];
    const float* bias   = (const float*)d_in[3];
    float* out = (float*)d_out;

    // 1) out = bias (broadcast over rows); 64*11008/4 float4 = 176128 -> 688 blocks
    init_bias_kernel<<<688, 256, 0, stream>>>(bias, out);

    // 2) GEMM with K-split atomically accumulating
    dim3 grid(N_DIM / BLOCK_N, KSPLIT);  // (172, 8)
    qlinear_kernel<<<grid, 256, 0, stream>>>(x, wq, scale, out);
}